// Round 1
// 720.787 us; speedup vs baseline: 1.1575x; 1.1575x over previous
//
#include <hip/hip_runtime.h>
#include <hip/hip_bf16.h>

typedef __attribute__((ext_vector_type(8))) __bf16 bf16x8;
typedef __attribute__((ext_vector_type(4))) __bf16 bf16x4;
typedef __attribute__((ext_vector_type(4))) float  f32x4;

#define L_LEN   8192
#define D_DIM   2048
#define G_NUM   256
#define HP      8320     // per-copy length of Hrev8 (elems), incl. 64-front/64-back zero pad
#define HS      808      // LDS per-copy stride (elems) -> 404 dwords, %32=20
#define KVS     264      // LDS kv row stride (elems) -> 132 dwords, %32=4

// ---- pass 1: kv = x2*v, transpose (b,l,d) -> [g][c=b*8+dg][l], cast bf16 ----
// No LDS: each thread owns one channel column (d fixed) x 16 l's. Global loads
// are coalesced across lanes (consecutive d); stores are two bf16x8 along l.
__global__ __launch_bounds__(256) void prep_kv_kernel(
    const float* __restrict__ x2, const float* __restrict__ v,
    __bf16* __restrict__ kvout)
{
  const int tid = threadIdx.x;
  const int l0 = blockIdx.x << 6;
  const int d0 = blockIdx.y << 6;
  const int b  = blockIdx.z;
  const int dl = tid & 63;          // d-local
  const int lc = tid >> 6;          // l-chunk (16 l's)
  const int gch = d0 + dl;
  const int row = ((gch >> 3) << 4) + (b << 3) + (gch & 7);  // g*16 + b*8 + dg
  const size_t ibase = ((size_t)(b * L_LEN + l0 + (lc << 4))) * D_DIM + gch;
  bf16x8 a0, a1;
#pragma unroll
  for (int k = 0; k < 8; ++k) {
    const size_t i0 = ibase + (size_t)k * D_DIM;
    const size_t i1 = ibase + (size_t)(k + 8) * D_DIM;
    a0[k] = (__bf16)(x2[i0] * v[i0]);
    a1[k] = (__bf16)(x2[i1] * v[i1]);
  }
  __bf16* dst = kvout + (size_t)row * L_LEN + l0 + (lc << 4);
  *(bf16x8*)dst = a0;
  *(bf16x8*)(dst + 8) = a1;
}

// ---- pass 2: Hrev8[g][s][z] = Hrev(z - 64 + s), Hrev(x) = h[g][8191 - x] (0 outside) ----
__global__ __launch_bounds__(256) void prep_h_kernel(
    const float* __restrict__ h, __bf16* __restrict__ hr)
{
  const unsigned i = blockIdx.x * 256u + threadIdx.x;
  const unsigned g = i / (8u * HP);
  const unsigned r = i - g * (8u * HP);
  const unsigned s = r / HP;
  const unsigned z = r - s * HP;
  const int P = 8255 - (int)z - (int)s;
  __bf16 val = (__bf16)0.0f;
  if (P >= 0 && P < 8192) val = (__bf16)h[(size_t)g * 8192 + P];
  hr[i] = val;
}

// ---- pass 3: Toeplitz MFMA conv + bias + x1 gating + transpose-out ----
// block: one group g, 512 l; 4 waves x 8 M-tiles(16 l); N=16 channels.
// K super-iter = 256 taps (8 jj sub-blocks of 32). A-frags (h Toeplitz) are
// held in a rolling 8-register window keyed by f&7 where f = 7 + 2*jj - i:
// 22 ds_read_b128 feed 64 MFMAs (was 32 reads per 32 MFMAs) -> LDS read BW,
// the measured bottleneck (MfmaUtil 25% w/ 1527 GB/s HBM), is roughly halved.
// Causality guards are gone: Hrev8's zero padding makes out-of-window taps
// contribute exact zeros, so unguarded MFMAs are correct; only a wave-uniform
// "wave finished" skip remains.
__global__ __launch_bounds__(256, 4) void conv_kernel(
    const __bf16* __restrict__ KV, const __bf16* __restrict__ HR,
    const float* __restrict__ x1, const float* __restrict__ bias,
    float* __restrict__ out)
{
  __shared__ __bf16 sKV[16 * KVS];
  __shared__ __bf16 sH[8 * HS];

  const int g   = blockIdx.x;
  const int jb  = 15 - (int)blockIdx.y;  // heavy l-blocks first
  const int l0  = jb << 9;
  const int tid = threadIdx.x;
  const int lane = tid & 63, wv = tid >> 6;
  const int m = lane & 15, q = lane >> 4;

  const __bf16* __restrict__ KVg = KV + (size_t)g * (16 * L_LEN);
  const __bf16* __restrict__ HRg = HR + (size_t)g * (8 * HP);

  f32x4 acc0 = {0.f,0.f,0.f,0.f}, acc1 = acc0, acc2 = acc0, acc3 = acc0,
        acc4 = acc0, acc5 = acc0, acc6 = acc0, acc7 = acc0;

  bf16x8 zed;
#pragma unroll
  for (int k = 0; k < 8; ++k) zed[k] = (__bf16)0.0f;

  const int cst = tid >> 4, tst = (tid & 15) << 3;  // kv staging: row, 8-elem chunk
  const int s_c   = (7 - m) & 7;                    // lane's shift-copy
  const int bbase = m * KVS + (q << 3);             // B-frag: n = lane&15, k-block = q
  const int wend  = l0 + (wv << 7) + 128;           // wave needs taps tb < wend

  const int send = l0 + 512;
  for (int tb = 0; tb < send; tb += 256) {
    __syncthreads();
    // stage kv[g][c][tb..tb+256)
    {
      const __bf16* src = &KVg[cst * L_LEN + tb + tst];
      *(bf16x8*)&sKV[cst * KVS + tst]       = *(const bf16x8*)src;
      *(bf16x8*)&sKV[cst * KVS + tst + 128] = *(const bf16x8*)(src + 128);
    }
    // stage h window: 8 copies x 784 elems
    const int Bv = 8255 - l0 + tb;
    const int Y0 = (Bv - 518) & ~7;
    for (int u = tid; u < 8 * 98; u += 256) {
      const int s   = u / 98;
      const int off = (u - s * 98) << 3;
      const int yy  = Y0 + off;
      bf16x8 w = zed;
      if (yy + 8 <= HP) w = *(const bf16x8*)&HRg[s * HP + yy];
      *(bf16x8*)&sH[s * HS + off] = w;
    }
    __syncthreads();

    if (tb >= wend) continue;  // wave-uniform; all waves re-converge at top barrier

    const int zbase = Bv - (wv << 7) - m + (q << 3);
    const int abase = s_c * HS + (zbase - s_c - Y0) - 112;  // A-frag f -> abase + 16*f

#define AFR(f) (*(const bf16x8*)&sH[abase + ((f) << 4)])
#define BFR(j) (*(const bf16x8*)&sKV[bbase + ((j) << 5)])
#define MF(ac, ar) ac = __builtin_amdgcn_mfma_f32_16x16x32_bf16(ar, bq, ac, 0, 0, 0)
    bf16x8 a0=AFR(0),a1=AFR(1),a2=AFR(2),a3=AFR(3),a4=AFR(4),a5=AFR(5),a6=AFR(6),a7=AFR(7);
    bf16x8 bq;
    bq = BFR(0);  // jj=0: f = 7-i
    MF(acc0,a7); MF(acc1,a6); MF(acc2,a5); MF(acc3,a4); MF(acc4,a3); MF(acc5,a2); MF(acc6,a1); MF(acc7,a0);
    a0 = AFR(8);  a1 = AFR(9);  bq = BFR(1);  // jj=1: f = 9-i
    MF(acc0,a1); MF(acc1,a0); MF(acc2,a7); MF(acc3,a6); MF(acc4,a5); MF(acc5,a4); MF(acc6,a3); MF(acc7,a2);
    a2 = AFR(10); a3 = AFR(11); bq = BFR(2);  // jj=2: f = 11-i
    MF(acc0,a3); MF(acc1,a2); MF(acc2,a1); MF(acc3,a0); MF(acc4,a7); MF(acc5,a6); MF(acc6,a5); MF(acc7,a4);
    a4 = AFR(12); a5 = AFR(13); bq = BFR(3);  // jj=3: f = 13-i
    MF(acc0,a5); MF(acc1,a4); MF(acc2,a3); MF(acc3,a2); MF(acc4,a1); MF(acc5,a0); MF(acc6,a7); MF(acc7,a6);
    a6 = AFR(14); a7 = AFR(15); bq = BFR(4);  // jj=4: f = 15-i
    MF(acc0,a7); MF(acc1,a6); MF(acc2,a5); MF(acc3,a4); MF(acc4,a3); MF(acc5,a2); MF(acc6,a1); MF(acc7,a0);
    a0 = AFR(16); a1 = AFR(17); bq = BFR(5);  // jj=5: f = 17-i
    MF(acc0,a1); MF(acc1,a0); MF(acc2,a7); MF(acc3,a6); MF(acc4,a5); MF(acc5,a4); MF(acc6,a3); MF(acc7,a2);
    a2 = AFR(18); a3 = AFR(19); bq = BFR(6);  // jj=6: f = 19-i
    MF(acc0,a3); MF(acc1,a2); MF(acc2,a1); MF(acc3,a0); MF(acc4,a7); MF(acc5,a6); MF(acc6,a5); MF(acc7,a4);
    a4 = AFR(20); a5 = AFR(21); bq = BFR(7);  // jj=7: f = 21-i
    MF(acc0,a5); MF(acc1,a4); MF(acc2,a3); MF(acc3,a2); MF(acc4,a1); MF(acc5,a0); MF(acc6,a7); MF(acc7,a6);
#undef MF
#undef BFR
#undef AFR
  }

  // epilogue: y += kv*bias; out = x1 * y, scattered back to (b,l,d)
  const int c = m;
  const int bb = c >> 3, dg = c & 7;
  const float bv = bias[(g << 3) + dg];

#define CONV_EPI(i, accv) {                                                     \
    const int l = l0 + (wv << 7) + ((i) << 4) + (q << 2);                       \
    const bf16x4 kv4 = *(const bf16x4*)&KVg[c * L_LEN + l];                     \
    for (int r = 0; r < 4; ++r) {                                               \
      const float y = accv[r] + (float)kv4[r] * bv;                             \
      const size_t oidx = ((size_t)(bb * L_LEN + l + r)) * D_DIM + (g << 3) + dg;\
      out[oidx] = x1[oidx] * y;                                                 \
    } }

  CONV_EPI(0, acc0)
  CONV_EPI(1, acc1)
  CONV_EPI(2, acc2)
  CONV_EPI(3, acc3)
  CONV_EPI(4, acc4)
  CONV_EPI(5, acc5)
  CONV_EPI(6, acc6)
  CONV_EPI(7, acc7)
#undef CONV_EPI
}

extern "C" void kernel_launch(void* const* d_in, const int* in_sizes, int n_in,
                              void* d_out, int out_size, void* d_ws, size_t ws_size,
                              hipStream_t stream)
{
  const float* x1 = (const float*)d_in[0];
  const float* x2 = (const float*)d_in[1];
  const float* v  = (const float*)d_in[2];
  const float* h  = (const float*)d_in[3];
  const float* cb = (const float*)d_in[4];
  float* out = (float*)d_out;

  // workspace: kv bf16 [256][16][8192] = 64 MiB, then Hrev8 bf16 [256][8][8320] = 32.5 MiB
  __bf16* kv = (__bf16*)d_ws;
  __bf16* hr = kv + (size_t)G_NUM * 16 * L_LEN;

  prep_kv_kernel<<<dim3(L_LEN / 64, D_DIM / 64, 2), 256, 0, stream>>>(x2, v, kv);
  prep_h_kernel<<<(G_NUM * 8 * HP) / 256, 256, 0, stream>>>(h, hr);
  conv_kernel<<<dim3(G_NUM, 16), 256, 0, stream>>>(kv, hr, x1, cb, out);
}

// Round 2
// 694.279 us; speedup vs baseline: 1.2017x; 1.0382x over previous
//
#include <hip/hip_runtime.h>
#include <hip/hip_bf16.h>

typedef __attribute__((ext_vector_type(8))) __bf16 bf16x8;
typedef __attribute__((ext_vector_type(4))) __bf16 bf16x4;
typedef __attribute__((ext_vector_type(4))) float  f32x4;

#define L_LEN   8192
#define D_DIM   2048
#define G_NUM   256
#define HP      8320     // per-copy length of Hrev8 (elems), incl. 64-front/64-back zero pad
#define HS      808      // LDS per-copy stride (elems) -> 404 dwords, %32=20
#define KVS     264      // LDS kv row stride (elems) -> 132 dwords, %32=4

// ---- pass 1: kv = x2*v, transpose (b,l,d) -> [g][c=b*8+dg][l], cast bf16 ----
// LDS tile transpose, 128l x 64d per block. float4 loads (coalesced 256B/16
// lanes); XOR-swizzled [ll][64] tile (d-block index ^ (ll>>3)) so b64 writes
// are conflict-free AND the transposed scalar reads hit disjoint bank sets
// (a +pad stride can't do both: reads want odd stride, b64 writes want %4=0).
// Stores: 8 lanes cover 256B contiguous of one kv row -> full lines.
__global__ __launch_bounds__(256) void prep_kv_kernel(
    const float* __restrict__ x2, const float* __restrict__ v,
    __bf16* __restrict__ kvout)
{
  __shared__ __bf16 sT[128 * 64];
  const int tid = threadIdx.x;
  const int l0 = blockIdx.x << 7;
  const int d0 = blockIdx.y << 6;
  const int b  = blockIdx.z;
  const int lr = tid >> 4;           // row-within-pass
  const int dq = tid & 15;           // d4-block
#pragma unroll
  for (int p = 0; p < 8; ++p) {
    const int ll = (p << 4) + lr;
    const size_t idx = ((size_t)(b * L_LEN + l0 + ll)) * D_DIM + d0 + (dq << 2);
    const f32x4 a = *(const f32x4*)&x2[idx];
    const f32x4 c = *(const f32x4*)&v[idx];
    bf16x4 kvv;
    kvv[0] = (__bf16)(a[0] * c[0]);
    kvv[1] = (__bf16)(a[1] * c[1]);
    kvv[2] = (__bf16)(a[2] * c[2]);
    kvv[3] = (__bf16)(a[3] * c[3]);
    *(bf16x4*)&sT[(ll << 6) + (((dq ^ (ll >> 3)) & 15) << 2)] = kvv;
  }
  __syncthreads();
#pragma unroll
  for (int p = 0; p < 2; ++p) {
    const int c  = tid + (p << 8);
    const int r  = c >> 3, seg = c & 7;   // r: d-local row, seg: 16-elem l-chunk
    const int rb = r >> 2, rl = r & 3;
    const int gch = d0 + r;
    const int row = ((gch >> 3) << 4) + (b << 3) + (gch & 7);  // g*16 + b*8 + dg
    bf16x8 w0, w1;
#pragma unroll
    for (int j = 0; j < 8; ++j) {
      const int lj0 = (seg << 4) + j;
      const int lj1 = lj0 + 8;
      w0[j] = sT[(lj0 << 6) + (((rb ^ (lj0 >> 3)) & 15) << 2) + rl];
      w1[j] = sT[(lj1 << 6) + (((rb ^ (lj1 >> 3)) & 15) << 2) + rl];
    }
    __bf16* dst = kvout + (size_t)row * L_LEN + l0 + (seg << 4);
    *(bf16x8*)dst = w0;
    *(bf16x8*)(dst + 8) = w1;
  }
}

// ---- pass 2: Hrev8[g][s][z] = Hrev(z - 64 + s), Hrev(x) = h[g][8191 - x] (0 outside) ----
__global__ __launch_bounds__(256) void prep_h_kernel(
    const float* __restrict__ h, __bf16* __restrict__ hr)
{
  const unsigned i = blockIdx.x * 256u + threadIdx.x;
  const unsigned g = i / (8u * HP);
  const unsigned r = i - g * (8u * HP);
  const unsigned s = r / HP;
  const unsigned z = r - s * HP;
  const int P = 8255 - (int)z - (int)s;
  __bf16 val = (__bf16)0.0f;
  if (P >= 0 && P < 8192) val = (__bf16)h[(size_t)g * 8192 + P];
  hr[i] = val;
}

// ---- pass 3: Toeplitz MFMA conv + bias + x1 gating + transpose-out ----
// block: one group g, 512 l; 4 waves x 8 M-tiles(16 l); N=16 channels.
// K super-iter = 256 taps, rolling 8-register A-window (round-1, verified).
// NEW: T14/T3 minimum-2-phase pipeline — double-buffered LDS; per iter:
// {issue next tile's global loads -> regs | compute buf[cur] | ds_write
// buf[cur^1] | ONE barrier}. Global-load latency hides under the MFMA phase
// instead of stalling all waves between two barriers (the measured gap:
// MfmaUtil 39% vs a 136us MFMA floor on a 326us kernel).
__global__ __launch_bounds__(256, 3) void conv_kernel(
    const __bf16* __restrict__ KV, const __bf16* __restrict__ HR,
    const float* __restrict__ x1, const float* __restrict__ bias,
    float* __restrict__ out)
{
  __shared__ __bf16 sKV[2][16 * KVS];
  __shared__ __bf16 sH[2][8 * HS];

  const int g   = blockIdx.x;
  const int jb  = 15 - (int)blockIdx.y;  // heavy l-blocks first
  const int l0  = jb << 9;
  const int tid = threadIdx.x;
  const int lane = tid & 63, wv = tid >> 6;
  const int m = lane & 15, q = lane >> 4;

  const __bf16* __restrict__ KVg = KV + (size_t)g * (16 * L_LEN);
  const __bf16* __restrict__ HRg = HR + (size_t)g * (8 * HP);

  f32x4 acc0 = {0.f,0.f,0.f,0.f}, acc1 = acc0, acc2 = acc0, acc3 = acc0,
        acc4 = acc0, acc5 = acc0, acc6 = acc0, acc7 = acc0;

  bf16x8 zed;
#pragma unroll
  for (int k = 0; k < 8; ++k) zed[k] = (__bf16)0.0f;

  const int cst = tid >> 4, tst = (tid & 15) << 3;  // kv staging: row, 8-elem chunk
  const int s_c   = (7 - m) & 7;                    // lane's shift-copy
  const int bbase = m * KVS + (q << 3);             // B-frag: n = lane&15, k-block = q
  const int wend  = l0 + (wv << 7) + 128;           // wave needs taps tb < wend

  // h staging geometry (t-invariant per thread): chunk u = tid + 256p, u < 784
  const int u0 = tid, u1 = tid + 256, u2 = tid + 512, u3 = tid + 768;
  const int sh0 = u0 / 98, sh1 = u1 / 98, sh2 = u2 / 98, sh3 = u3 / 98;
  const int o0 = (u0 - sh0 * 98) << 3, o1 = (u1 - sh1 * 98) << 3;
  const int o2 = (u2 - sh2 * 98) << 3, o3 = (u3 - sh3 * 98) << 3;
  const int w0 = sh0 * HS + o0, w1 = sh1 * HS + o1;
  const int w2 = sh2 * HS + o2, w3 = sh3 * HS + o3;
  const bool vld3 = (u3 < 8 * 98);  // tid < 16

  const int nt = (l0 + 512) >> 8;   // super-iters (>= 2)

  bf16x8 pkv0, pkv1, ph0, ph1, ph2, ph3;

#define STAGE_LOAD(tbn) do {                                                     \
    const int Bvn = 8255 - l0 + (tbn);                                           \
    const int Y0n = (Bvn - 518) & ~7;                                            \
    pkv0 = *(const bf16x8*)&KVg[cst * L_LEN + (tbn) + tst];                      \
    pkv1 = *(const bf16x8*)&KVg[cst * L_LEN + (tbn) + tst + 128];                \
    int yy;                                                                      \
    yy = Y0n + o0; ph0 = (yy + 8 <= HP) ? *(const bf16x8*)&HRg[sh0 * HP + yy] : zed; \
    yy = Y0n + o1; ph1 = (yy + 8 <= HP) ? *(const bf16x8*)&HRg[sh1 * HP + yy] : zed; \
    yy = Y0n + o2; ph2 = (yy + 8 <= HP) ? *(const bf16x8*)&HRg[sh2 * HP + yy] : zed; \
    yy = Y0n + o3; ph3 = (vld3 && yy + 8 <= HP) ? *(const bf16x8*)&HRg[sh3 * HP + yy] : zed; \
  } while (0)

#define STAGE_WRITE(bi) do {                                                     \
    *(bf16x8*)&sKV[bi][cst * KVS + tst]       = pkv0;                            \
    *(bf16x8*)&sKV[bi][cst * KVS + tst + 128] = pkv1;                            \
    *(bf16x8*)&sH[bi][w0] = ph0;                                                 \
    *(bf16x8*)&sH[bi][w1] = ph1;                                                 \
    *(bf16x8*)&sH[bi][w2] = ph2;                                                 \
    if (vld3) *(bf16x8*)&sH[bi][w3] = ph3;                                       \
  } while (0)

  // prologue: stage tile 0 into buffer 0
  STAGE_LOAD(0);
  STAGE_WRITE(0);
  __syncthreads();

  int cur = 0;
  for (int t = 0; t < nt; ++t) {
    const int tb = t << 8;
    const bool pf = (t + 1 < nt);
    if (pf) STAGE_LOAD(tb + 256);     // issue-early: latency hides under MFMA

    if (tb < wend) {
      const __bf16* __restrict__ sHc  = sH[cur];
      const __bf16* __restrict__ sKVc = sKV[cur];
      const int Bv = 8255 - l0 + tb;
      const int Y0 = (Bv - 518) & ~7;
      const int zbase = Bv - (wv << 7) - m + (q << 3);
      const int abase = s_c * HS + (zbase - s_c - Y0) - 112;  // A-frag f -> abase + 16*f

#define AFR(f) (*(const bf16x8*)&sHc[abase + ((f) << 4)])
#define BFR(j) (*(const bf16x8*)&sKVc[bbase + ((j) << 5)])
#define MF(ac, ar) ac = __builtin_amdgcn_mfma_f32_16x16x32_bf16(ar, bq, ac, 0, 0, 0)
      bf16x8 a0=AFR(0),a1=AFR(1),a2=AFR(2),a3=AFR(3),a4=AFR(4),a5=AFR(5),a6=AFR(6),a7=AFR(7);
      bf16x8 bq;
      bq = BFR(0);  // jj=0: f = 7-i
      MF(acc0,a7); MF(acc1,a6); MF(acc2,a5); MF(acc3,a4); MF(acc4,a3); MF(acc5,a2); MF(acc6,a1); MF(acc7,a0);
      a0 = AFR(8);  a1 = AFR(9);  bq = BFR(1);  // jj=1: f = 9-i
      MF(acc0,a1); MF(acc1,a0); MF(acc2,a7); MF(acc3,a6); MF(acc4,a5); MF(acc5,a4); MF(acc6,a3); MF(acc7,a2);
      a2 = AFR(10); a3 = AFR(11); bq = BFR(2);  // jj=2: f = 11-i
      MF(acc0,a3); MF(acc1,a2); MF(acc2,a1); MF(acc3,a0); MF(acc4,a7); MF(acc5,a6); MF(acc6,a5); MF(acc7,a4);
      a4 = AFR(12); a5 = AFR(13); bq = BFR(3);  // jj=3: f = 13-i
      MF(acc0,a5); MF(acc1,a4); MF(acc2,a3); MF(acc3,a2); MF(acc4,a1); MF(acc5,a0); MF(acc6,a7); MF(acc7,a6);
      a6 = AFR(14); a7 = AFR(15); bq = BFR(4);  // jj=4: f = 15-i
      MF(acc0,a7); MF(acc1,a6); MF(acc2,a5); MF(acc3,a4); MF(acc4,a3); MF(acc5,a2); MF(acc6,a1); MF(acc7,a0);
      a0 = AFR(16); a1 = AFR(17); bq = BFR(5);  // jj=5: f = 17-i
      MF(acc0,a1); MF(acc1,a0); MF(acc2,a7); MF(acc3,a6); MF(acc4,a5); MF(acc5,a4); MF(acc6,a3); MF(acc7,a2);
      a2 = AFR(18); a3 = AFR(19); bq = BFR(6);  // jj=6: f = 19-i
      MF(acc0,a3); MF(acc1,a2); MF(acc2,a1); MF(acc3,a0); MF(acc4,a7); MF(acc5,a6); MF(acc6,a5); MF(acc7,a4);
      a4 = AFR(20); a5 = AFR(21); bq = BFR(7);  // jj=7: f = 21-i
      MF(acc0,a5); MF(acc1,a4); MF(acc2,a3); MF(acc3,a2); MF(acc4,a1); MF(acc5,a0); MF(acc6,a7); MF(acc7,a6);
#undef MF
#undef BFR
#undef AFR
    }

    if (pf) STAGE_WRITE(cur ^ 1);     // write-late; safe: buf[cur^1] last read
                                      // before PREVIOUS barrier
    __syncthreads();
    cur ^= 1;
  }
#undef STAGE_LOAD
#undef STAGE_WRITE

  // epilogue: y += kv*bias; out = x1 * y, scattered back to (b,l,d)
  const int c = m;
  const int bb = c >> 3, dg = c & 7;
  const float bv = bias[(g << 3) + dg];

#define CONV_EPI(i, accv) {                                                     \
    const int l = l0 + (wv << 7) + ((i) << 4) + (q << 2);                       \
    const bf16x4 kv4 = *(const bf16x4*)&KVg[c * L_LEN + l];                     \
    for (int r = 0; r < 4; ++r) {                                               \
      const float y = accv[r] + (float)kv4[r] * bv;                             \
      const size_t oidx = ((size_t)(bb * L_LEN + l + r)) * D_DIM + (g << 3) + dg;\
      out[oidx] = x1[oidx] * y;                                                 \
    } }

  CONV_EPI(0, acc0)
  CONV_EPI(1, acc1)
  CONV_EPI(2, acc2)
  CONV_EPI(3, acc3)
  CONV_EPI(4, acc4)
  CONV_EPI(5, acc5)
  CONV_EPI(6, acc6)
  CONV_EPI(7, acc7)
#undef CONV_EPI
}

extern "C" void kernel_launch(void* const* d_in, const int* in_sizes, int n_in,
                              void* d_out, int out_size, void* d_ws, size_t ws_size,
                              hipStream_t stream)
{
  const float* x1 = (const float*)d_in[0];
  const float* x2 = (const float*)d_in[1];
  const float* v  = (const float*)d_in[2];
  const float* h  = (const float*)d_in[3];
  const float* cb = (const float*)d_in[4];
  float* out = (float*)d_out;

  // workspace: kv bf16 [256][16][8192] = 64 MiB, then Hrev8 bf16 [256][8][8320] = 32.5 MiB
  __bf16* kv = (__bf16*)d_ws;
  __bf16* hr = kv + (size_t)G_NUM * 16 * L_LEN;

  prep_kv_kernel<<<dim3(L_LEN / 128, D_DIM / 64, 2), 256, 0, stream>>>(x2, v, kv);
  prep_h_kernel<<<(G_NUM * 8 * HP) / 256, 256, 0, stream>>>(h, hr);
  conv_kernel<<<dim3(G_NUM, 16), 256, 0, stream>>>(kv, hr, x1, cb, out);
}